// Round 11
// baseline (121.509 us; speedup 1.0000x reference)
//
#include <hip/hip_runtime.h>
#include <hip/hip_bf16.h>

// GraphResBlock: B=8, N=256, F=64(N_IN), H=128(N_HID), E=16(EIN)
// pair[b,i,j,h] = e[b,i,j,:]@We[:,h] + x[b,j,:]@Wf[:,h] + net'[b,i,h]  (net' = x@Wt + bf+bt+be)
// k_pair: ne[b,i,h] = (sum_j relu(pair) - relu(pair[j=i]))/256   (diag extracted in-register)
// k_mlp : out = relu(ne@W1+b1)@W2+b2+x

#define BB 8
#define NN 256
#define FF 64
#define HH 128
#define EE 16
#define NCH 5   // K chunks for pair: 0 = We(16), 1..4 = Wf(64)

typedef __attribute__((ext_vector_type(8))) short bf16x8;
typedef __attribute__((ext_vector_type(16))) float f32x16;

__device__ __forceinline__ short f2bf(float f) {
    union { float f; unsigned u; } v; v.f = f;
    unsigned r = v.u + 0x7FFFu + ((v.u >> 16) & 1u);   // RNE
    return (short)(r >> 16);
}
// packed RNE conversion: dst = {bf16(lo), bf16(hi)}
__device__ __forceinline__ unsigned pkbf(float lo, float hi) {
    unsigned r;
    asm("v_cvt_pk_bf16_f32 %0, %1, %2" : "=v"(r) : "v"(lo), "v"(hi));
    return r;
}

// ---------------- Kernel 1: net' = x@Wt+(bf+bt+be); xbfp (frag-order); pack B'/W1/W2 ----------------
__global__ __launch_bounds__(128) void k_prep(
    const float* __restrict__ x, const float* __restrict__ Wt,
    const float* __restrict__ bf, const float* __restrict__ bt, const float* __restrict__ be,
    const float* __restrict__ We, const float* __restrict__ Wf,
    const float* __restrict__ W1, const float* __restrict__ W2,
    float* __restrict__ net, short* __restrict__ xbfp,
    short* __restrict__ Bpack, short* __restrict__ W1p, short* __restrict__ W2p)
{
    __shared__ float smx[4 * FF];
    const int tid = threadIdx.x;
    const int row0 = blockIdx.x * 4;

    smx[tid]       = x[(size_t)row0 * FF + tid];
    smx[tid + 128] = x[(size_t)row0 * FF + tid + 128];
    __syncthreads();

    const int h = tid;
    const float bsum = bf[h] + bt[h] + be[h];
    float a0 = bsum, a1 = bsum, a2 = bsum, a3 = bsum;

    #pragma unroll 8
    for (int k = 0; k < FF; ++k) {
        const float wt = Wt[k * HH + h];
        a0 = fmaf(smx[k], wt, a0);
        a1 = fmaf(smx[FF + k], wt, a1);
        a2 = fmaf(smx[2 * FF + k], wt, a2);
        a3 = fmaf(smx[3 * FF + k], wt, a3);
    }
    net[(size_t)(row0 + 0) * HH + h] = a0;
    net[(size_t)(row0 + 1) * HH + h] = a1;
    net[(size_t)(row0 + 2) * HH + h] = a2;
    net[(size_t)(row0 + 3) * HH + h] = a3;

    // x in MFMA fragment order: xbfp[bb][jt][ch][lane][el] (k = 16*ch + 8*half + el)
    {
        const int r    = tid >> 5;        // 0..3 local row
        const int q    = tid & 31;
        const int ch   = q >> 3;          // 0..3
        const int half = (q >> 2) & 1;
        const int el2  = q & 3;
        const int gj   = row0 + r;
        const int bb   = gj >> 8;
        const int jj   = gj & 255;
        const int jt   = jj >> 5;
        const int cc   = jj & 31;
        const float lo = smx[r * FF + ch * 16 + half * 8 + el2 * 2];
        const float hi = smx[r * FF + ch * 16 + half * 8 + el2 * 2 + 1];
        ((unsigned*)xbfp)[((((size_t)bb * 8 + jt) * 4 + ch) * 64 + half * 32 + cc) * 4 + el2]
            = pkbf(lo, hi);
    }

    // ---- pack B'=[We;Wf] (10240), W1 (16384), W2 (8192) into MFMA frag layout ----
    // layout [ch][ht][lane][el]: k = 16*ch_local + 8*(lane>>5) + el, h = ht*32 + (lane&31)
    if (blockIdx.x < 32) {
        for (int t = blockIdx.x * 128 + tid; t < 34816; t += 32 * 128) {
            if (t < 10240) {
                const int el = t & 7, lane = (t >> 3) & 63, ht = (t >> 9) & 3, ch = t >> 11;
                const int kl = 8 * (lane >> 5) + el;
                const int hh = ht * 32 + (lane & 31);
                Bpack[t] = f2bf(ch == 0 ? We[kl * HH + hh] : Wf[(16 * (ch - 1) + kl) * HH + hh]);
            } else if (t < 26624) {
                const int t2 = t - 10240;
                const int el = t2 & 7, lane = (t2 >> 3) & 63, ht = (t2 >> 9) & 3, ch = (t2 >> 11) & 7;
                const int k = 16 * ch + 8 * (lane >> 5) + el;
                const int hh = ht * 32 + (lane & 31);
                W1p[t2] = f2bf(W1[k * HH + hh]);
            } else {
                const int t3 = t - 26624;
                const int el = t3 & 7, lane = (t3 >> 3) & 63, ht = (t3 >> 9) & 1, ch = t3 >> 10;
                const int k = 16 * ch + 8 * (lane >> 5) + el;
                const int hh = ht * 32 + (lane & 31);
                W2p[t3] = f2bf(W2[k * FF + hh]);
            }
        }
    }
}

// ---------------- Kernel 2: ne[b,i,h] (whole-row LDS e + LDS-staged x, in-register diag) ----------------
// One block per (b,i), 4 waves; wave w owns h-tile w; j-loop barrier-free.
__global__ __launch_bounds__(256) void k_pair(
    const float* __restrict__ e, const float* __restrict__ net,
    const short* __restrict__ xbfp, const short* __restrict__ Bpack,
    short* __restrict__ neb)
{
    const int row  = blockIdx.x;            // b*256 + i
    const int b    = row >> 8;
    const int i    = row & (NN - 1);
    const int tid  = threadIdx.x;
    const int wave = tid >> 6;              // my h-tile
    const int lane = tid & 63;
    const int c    = lane & 31;
    const int half = lane >> 5;

    // whole e-row bf16 [jt][half][c][k8] = 8 KB; x fragments [jt][ch][lane] = 32 KB
    __shared__ __align__(16) char eL[8 * 1024];
    __shared__ __align__(16) char xL[32 * 1024];

    const bf16x8* __restrict__ bp = (const bf16x8*)Bpack;
    bf16x8 bfrag[NCH];
    #pragma unroll
    for (int ch = 0; ch < NCH; ++ch)
        bfrag[ch] = bp[(ch * 4 + wave) * 64 + lane];

    const float netv = net[(size_t)row * HH + wave * 32 + c];

    const float* __restrict__ eRow = e + (size_t)row * (NN * EE);
    const uint4* __restrict__ xqg  = (const uint4*)(xbfp + (size_t)b * 8 * 4 * 512);

    // stage x fragments: 2048 uint4, 8 per thread, coalesced
    #pragma unroll
    for (int k = 0; k < 8; ++k)
        ((uint4*)xL)[k * 256 + tid] = xqg[k * 256 + tid];

    // stage e row: thread t holds (row sc, k=2*sk2, 2*sk2+1) of each tile
    const int sc   = tid >> 3;
    const int sk2  = tid & 7;
    const int edst = ((sk2 >> 2) * 128 + sc * 4 + (sk2 & 3)) * 4;
    #pragma unroll
    for (int jt = 0; jt < 8; ++jt) {
        const float2 ev = *(const float2*)(eRow + (size_t)jt * 512 + tid * 2);
        *(unsigned*)(&eL[jt * 1024 + edst]) = pkbf(ev.x, ev.y);
    }
    __syncthreads();

    // diagonal locator: pair[i,i,h] lives at jt*=i>>5, reg r*, half*
    const int tloc     = i & 31;
    const int jtstar   = i >> 5;
    const int halfstar = (tloc >> 2) & 1;
    const int rstar    = (tloc & 3) + 4 * (tloc >> 3);
    float dgv = 0.f;

    float acc0 = 0.f, acc1 = 0.f, acc2 = 0.f, acc3 = 0.f;
    const bf16x8* __restrict__ xf = (const bf16x8*)xL;

    #pragma unroll
    for (int jt = 0; jt < 8; ++jt) {
        const bf16x8 ae  = *(const bf16x8*)(&eL[jt * 1024 + half * 512 + c * 16]);
        const bf16x8 ax0 = xf[(jt * 4 + 0) * 64 + lane];
        const bf16x8 ax1 = xf[(jt * 4 + 1) * 64 + lane];
        const bf16x8 ax2 = xf[(jt * 4 + 2) * 64 + lane];
        const bf16x8 ax3 = xf[(jt * 4 + 3) * 64 + lane];

        f32x16 d = {netv,netv,netv,netv, netv,netv,netv,netv,
                    netv,netv,netv,netv, netv,netv,netv,netv};
        d = __builtin_amdgcn_mfma_f32_32x32x16_bf16(ae,  bfrag[0], d, 0, 0, 0);
        d = __builtin_amdgcn_mfma_f32_32x32x16_bf16(ax0, bfrag[1], d, 0, 0, 0);
        d = __builtin_amdgcn_mfma_f32_32x32x16_bf16(ax1, bfrag[2], d, 0, 0, 0);
        d = __builtin_amdgcn_mfma_f32_32x32x16_bf16(ax2, bfrag[3], d, 0, 0, 0);
        d = __builtin_amdgcn_mfma_f32_32x32x16_bf16(ax3, bfrag[4], d, 0, 0, 0);

        if (jt == jtstar && half == halfstar) {    // extract diag value (exact)
            #pragma unroll
            for (int r = 0; r < 16; ++r) dgv = (r == rstar) ? d[r] : dgv;
        }

        #pragma unroll
        for (int r = 0; r < 16; r += 4) {
            acc0 += fmaxf(d[r + 0], 0.f);
            acc1 += fmaxf(d[r + 1], 0.f);
            acc2 += fmaxf(d[r + 2], 0.f);
            acc3 += fmaxf(d[r + 3], 0.f);
        }
    }

    float acc = (acc0 + acc1) + (acc2 + acc3);
    acc -= fmaxf(dgv, 0.f);                        // cancel diag (bitwise-exact term)
    acc += __shfl_xor(acc, 32);
    if (lane < 32)
        neb[(size_t)row * HH + wave * 32 + c] = f2bf(acc * (1.0f / (float)NN));
}

// ---------------- Kernel 3: MLP + residual (MFMA, no diag work) ----------------
// 64 blocks x 32 rows, 4 waves; wave w owns h-tile w.
__global__ __launch_bounds__(256) void k_mlp(
    const float* __restrict__ x, const short* __restrict__ neb,
    const short* __restrict__ W1p, const short* __restrict__ W2p,
    const float* __restrict__ b1, const float* __restrict__ b2,
    float* __restrict__ out)
{
    const int row0 = blockIdx.x * 32;
    const int tid  = threadIdx.x;
    const int wave = tid >> 6;
    const int lane = tid & 63;
    const int c    = lane & 31;
    const int half = lane >> 5;

    __shared__ short neL[32][136];       // ne bf16
    __shared__ short h1L[32][136];       // h1 bf16

    // stage ne rows (coalesced 32B/thread)
    {
        const int r  = tid >> 3;
        const int h0 = (tid & 7) * 16;
        const uint4* src = (const uint4*)&neb[(size_t)(row0 + r) * HH + h0];
        uint4* dst = (uint4*)&neL[r][h0];
        dst[0] = src[0];
        dst[1] = src[1];
    }
    __syncthreads();

    // ---- h1 = relu(ne @ W1 + b1), K=128 = 8 chunks ----
    {
        const float b1v = b1[wave * 32 + c];
        const bf16x8* wp = (const bf16x8*)W1p;
        f32x16 d = {b1v,b1v,b1v,b1v, b1v,b1v,b1v,b1v, b1v,b1v,b1v,b1v, b1v,b1v,b1v,b1v};
        #pragma unroll
        for (int ch = 0; ch < 8; ++ch) {
            const bf16x8 a = *(const bf16x8*)&neL[c][16 * ch + 8 * half];
            d = __builtin_amdgcn_mfma_f32_32x32x16_bf16(a, wp[(ch * 4 + wave) * 64 + lane], d, 0, 0, 0);
        }
        #pragma unroll
        for (int r = 0; r < 16; ++r) {
            const int rowj = (r & 3) + 8 * (r >> 2) + 4 * half;
            h1L[rowj][wave * 32 + c] = f2bf(fmaxf(d[r], 0.f));
        }
    }
    __syncthreads();

    // ---- out = h1 @ W2 + b2 + x, N=64 -> waves 0,1 ----
    if (wave < 2) {
        const float b2v = b2[wave * 32 + c];
        const bf16x8* wp = (const bf16x8*)W2p;
        f32x16 d = {b2v,b2v,b2v,b2v, b2v,b2v,b2v,b2v, b2v,b2v,b2v,b2v, b2v,b2v,b2v,b2v};
        #pragma unroll
        for (int ch = 0; ch < 8; ++ch) {
            const bf16x8 a = *(const bf16x8*)&h1L[c][16 * ch + 8 * half];
            d = __builtin_amdgcn_mfma_f32_32x32x16_bf16(a, wp[(ch * 2 + wave) * 64 + lane], d, 0, 0, 0);
        }
        #pragma unroll
        for (int r = 0; r < 16; ++r) {
            const int rowj = (r & 3) + 8 * (r >> 2) + 4 * half;
            const size_t idx = (size_t)(row0 + rowj) * FF + wave * 32 + c;
            out[idx] = d[r] + x[idx];
        }
    }
}

extern "C" void kernel_launch(void* const* d_in, const int* in_sizes, int n_in,
                              void* d_out, int out_size, void* d_ws, size_t ws_size,
                              hipStream_t stream) {
    (void)in_sizes; (void)n_in; (void)out_size; (void)ws_size;
    const float* x  = (const float*)d_in[0];
    const float* e  = (const float*)d_in[1];
    const float* Wf = (const float*)d_in[2];
    const float* bf = (const float*)d_in[3];
    const float* Wt = (const float*)d_in[4];
    const float* bt = (const float*)d_in[5];
    const float* We = (const float*)d_in[6];
    const float* be = (const float*)d_in[7];
    const float* W1 = (const float*)d_in[8];
    const float* b1 = (const float*)d_in[9];
    const float* W2 = (const float*)d_in[10];
    const float* b2 = (const float*)d_in[11];
    float* out = (float*)d_out;

    // ws: net 1MB | neb 512KB | xbfp 256KB | Bpack 20KB | W1p 32KB | W2p 16KB
    char* w = (char*)d_ws;
    float* net   = (float*)w;                 w += (size_t)BB * NN * HH * 4;
    short* neb   = (short*)w;                 w += (size_t)BB * NN * HH * 2;
    short* xbfp  = (short*)w;                 w += (size_t)BB * NN * FF * 2;
    short* Bpack = (short*)w;                 w += NCH * 4 * 64 * 8 * 2;
    short* W1p   = (short*)w;                 w += 8 * 4 * 64 * 8 * 2;
    short* W2p   = (short*)w;

    k_prep<<<(BB * NN) / 4, 128, 0, stream>>>(x, Wt, bf, bt, be, We, Wf, W1, W2,
                                              net, xbfp, Bpack, W1p, W2p);
    k_pair<<<BB * NN, 256, 0, stream>>>(e, net, xbfp, Bpack, neb);
    k_mlp<<<(BB * NN) / 32, 256, 0, stream>>>(x, neb, W1p, W2p, b1, b2, out);
}